// Round 12
// baseline (1335.898 us; speedup 1.0000x reference)
//
#include <hip/hip_runtime.h>
#include <stdint.h>

typedef unsigned short u16;
typedef unsigned int u32;
typedef short bf16x8 __attribute__((ext_vector_type(8)));
typedef float f32x4 __attribute__((ext_vector_type(4)));

#define E_ 8
#define H_ 2048
#define F_ 4096
#define T_ 16384
#define TE_ 2048

#define WAITV(n) asm volatile("s_waitcnt vmcnt(" #n ")" ::: "memory")
#define LGKM0 asm volatile("s_waitcnt lgkmcnt(0)" ::: "memory")
#define BARF                       \
  do {                             \
    asm volatile("" ::: "memory"); \
    __builtin_amdgcn_s_barrier();  \
    asm volatile("" ::: "memory"); \
  } while (0)

__device__ __forceinline__ u16 f2bf(float f) {
  u32 u = __builtin_bit_cast(u32, f);
  u32 r = (u + 0x7FFFu + ((u >> 16) & 1u)) >> 16;  // RNE
  return (u16)r;
}

// packed 2xfp32 -> 2xbf16 (RNE); lo16 = first operand
__device__ __forceinline__ u32 cvtpk(float lo, float hi) {
  u32 r;
  asm("v_cvt_pk_bf16_f32 %0, %1, %2" : "=v"(r) : "v"(lo), "v"(hi));
  return r;
}

__device__ __forceinline__ void gload16(const u16* g, u16* l) {
  __builtin_amdgcn_global_load_lds(
      (__attribute__((address_space(1))) void*)g,
      (__attribute__((address_space(3))) void*)l, 16, 0, 0);
}

__device__ __forceinline__ void mfma_b(f32x4& acc, bf16x8 a, bf16x8 b) {
  asm volatile("v_mfma_f32_16x16x32_bf16 %0, %1, %2, %0"
               : "+v"(acc)
               : "v"(a), "v"(b));
}

// 8 NAMED float4 regs per staging set (no arrays -> no scratch, rule #20).
// NOTE: paste digit alone, then parenthesized member access — `p##0.x`
// lexes `0.x` as one pp-number and fails to paste (round-11 bug).
#define DECL_RB(p) float4 p##0, p##1, p##2, p##3, p##4, p##5, p##6, p##7

#define LOADB(p, t)                      \
  do {                                   \
    const size_t kt_ = (size_t)(t) * 16; \
    p##0 = gB4[r0_ + kt_];               \
    p##1 = gB4[r0_ + kt_ + 1];           \
    p##2 = gB4[r1_ + kt_];               \
    p##3 = gB4[r1_ + kt_ + 1];           \
    p##4 = gB4[r2_ + kt_];               \
    p##5 = gB4[r2_ + kt_ + 1];           \
    p##6 = gB4[r3_ + kt_];               \
    p##7 = gB4[r3_ + kt_ + 1];           \
  } while (0)

#define WRITEB(buf, p)                    \
  do {                                    \
    u16* Lw_ = lds + (buf)*16384;         \
    uint4 v_;                             \
    v_.x = cvtpk((p##0).x, (p##0).y);     \
    v_.y = cvtpk((p##0).z, (p##0).w);     \
    v_.z = cvtpk((p##1).x, (p##1).y);     \
    v_.w = cvtpk((p##1).z, (p##1).w);     \
    *(uint4*)&Lw_[o0_] = v_;              \
    v_.x = cvtpk((p##2).x, (p##2).y);     \
    v_.y = cvtpk((p##2).z, (p##2).w);     \
    v_.z = cvtpk((p##3).x, (p##3).y);     \
    v_.w = cvtpk((p##3).z, (p##3).w);     \
    *(uint4*)&Lw_[o1_] = v_;              \
    v_.x = cvtpk((p##4).x, (p##4).y);     \
    v_.y = cvtpk((p##4).z, (p##4).w);     \
    v_.z = cvtpk((p##5).x, (p##5).y);     \
    v_.w = cvtpk((p##5).z, (p##5).w);     \
    *(uint4*)&Lw_[o2_] = v_;              \
    v_.x = cvtpk((p##6).x, (p##6).y);     \
    v_.y = cvtpk((p##6).z, (p##6).w);     \
    v_.z = cvtpk((p##7).x, (p##7).y);     \
    v_.w = cvtpk((p##7).z, (p##7).w);     \
    *(uint4*)&Lw_[o3_] = v_;              \
  } while (0)

// ---------- fp32 -> bf16 convert (x only) ----------

__global__ __launch_bounds__(256) void cvt_kernel(const float* __restrict__ src,
                                                  u16* __restrict__ dst,
                                                  long n4) {
  long i = (long)blockIdx.x * blockDim.x + threadIdx.x;
  long stride = (long)gridDim.x * blockDim.x;
  const float4* s4 = (const float4*)src;
  uint2* d4 = (uint2*)dst;
  for (; i < n4; i += stride) {
    float4 v = s4[i];
    uint2 o;
    o.x = (u32)f2bf(v.x) | ((u32)f2bf(v.y) << 16);
    o.y = (u32)f2bf(v.z) | ((u32)f2bf(v.w) << 16);
    d4[i] = o;
  }
}

// ============ GEMM1 fused: hidden = silu(x@Wg^T) * (x@Wu^T) ============
// Round-8 proven structure; weights reg-staged from FP32 via named regs.

__global__ __launch_bounds__(256, 2) void gemm1_silu(
    const u16* __restrict__ Xb, const float* __restrict__ Wgu,
    u16* __restrict__ Hid, long sX, long sW, long sH) {
  const int z = blockIdx.z;
  Xb += (long)z * sX;
  Wgu += (long)z * sW;
  Hid += (long)z * sH;

  const int bx = blockIdx.x;  // hidden-col tile (64)
  const int by = blockIdx.y;  // row tile (128)
  const int tid = threadIdx.x;
  const int w = tid >> 6;
  const int lane = tid & 63;
  const int wr = w >> 1, wc = w & 1;
  const int fr = lane & 15, q = lane >> 4, l7 = lane & 7;

  __shared__ __attribute__((aligned(16))) u16 lds[2 * 16384];

  const int srow8 = lane >> 3;
  const int sgran = (lane & 7) ^ (lane >> 3);
  const u16* gA = Xb + (size_t)(by * 128 + srow8) * H_ + sgran * 8;
  const float4* gB4 =
      (const float4*)Wgu + (size_t)(bx * 64 + srow8) * (H_ / 4) + sgran * 2;

  // chunk row offsets (float4 units): c0=w,c1=4+w (gate); c2,c3 = up
  const size_t r0_ = (size_t)w * 8 * (H_ / 4);
  const size_t r1_ = (size_t)(4 + w) * 8 * (H_ / 4);
  const size_t r2_ = (size_t)F_ * (H_ / 4) + r0_;
  const size_t r3_ = (size_t)F_ * (H_ / 4) + r1_;
  // LDS elem offsets for B chunks (B base 8192)
  const int o0_ = 8192 + w * 512 + lane * 8;
  const int o1_ = 8192 + (4 + w) * 512 + lane * 8;
  const int o2_ = 8192 + (8 + w) * 512 + lane * 8;
  const int o3_ = 8192 + (12 + w) * 512 + lane * 8;

  auto stageA = [&](int t, int buf) {
    u16* L = lds + buf * 16384;
    const int ko = t * 64;
#pragma unroll
    for (int i = 0; i < 4; ++i) {
      const int c = i * 4 + w;
      gload16(gA + (size_t)(c * 8) * H_ + ko, L + c * 512 + lane * 8);
    }
  };

  f32x4 accG[4][2] = {};
  f32x4 accU[4][2] = {};

  auto comp = [&](int buf) {
    const u16* L = lds + buf * 16384;
#pragma unroll
    for (int ks = 0; ks < 2; ++ks) {
      const int seg = (((ks << 2) + q) ^ l7) << 3;
      bf16x8 a[4], bg[2], bu[2];
#pragma unroll
      for (int mi = 0; mi < 4; ++mi)
        a[mi] = *(const bf16x8*)&L[(wr * 64 + mi * 16 + fr) * 64 + seg];
#pragma unroll
      for (int ni = 0; ni < 2; ++ni) {
        bg[ni] = *(const bf16x8*)&L[8192 + (wc * 32 + ni * 16 + fr) * 64 + seg];
        bu[ni] =
            *(const bf16x8*)&L[12288 + (wc * 32 + ni * 16 + fr) * 64 + seg];
      }
      __builtin_amdgcn_s_setprio(1);
#pragma unroll
      for (int mi = 0; mi < 4; ++mi)
#pragma unroll
        for (int ni = 0; ni < 2; ++ni) {
          mfma_b(accG[mi][ni], a[mi], bg[ni]);
          mfma_b(accU[mi][ni], a[mi], bu[ni]);
        }
      __builtin_amdgcn_s_setprio(0);
    }
  };

  DECL_RB(pa);
  DECL_RB(pb);
  const int NT = H_ / 64;  // 32
  LOADB(pa, 0);
  stageA(0, 0);
  LOADB(pb, 1);
  stageA(1, 1);
  WAITV(16);
  WRITEB(0, pa);
  WAITV(12);
  LGKM0;
  BARF;
  for (int t = 0; t < NT - 2; t += 2) {
    comp(0);
    BARF;
    LOADB(pa, t + 2);
    stageA(t + 2, 0);
    WAITV(16);
    WRITEB(1, pb);
    WAITV(12);
    LGKM0;
    BARF;
    comp(1);
    BARF;
    LOADB(pb, t + 3);
    stageA(t + 3, 1);
    WAITV(16);
    WRITEB(0, pa);
    WAITV(12);
    LGKM0;
    BARF;
  }
  comp(0);
  BARF;
  WAITV(4);
  WRITEB(1, pb);
  WAITV(0);
  LGKM0;
  BARF;
  comp(1);

  const int row0 = by * 128 + wr * 64 + q * 4;
  const int col0 = bx * 64 + wc * 32 + fr;
#pragma unroll
  for (int mi = 0; mi < 4; ++mi)
#pragma unroll
    for (int ni = 0; ni < 2; ++ni)
#pragma unroll
      for (int j = 0; j < 4; ++j) {
        float g = accG[mi][ni][j];
        float u = accU[mi][ni][j];
        float h = (g / (1.f + __expf(-g))) * u;
        Hid[(size_t)(row0 + mi * 16 + j) * F_ + col0 + ni * 16] = f2bf(h);
      }
}

// ============ GEMM2: out = hidden @ w_down^T (fp32 out) ============

__global__ __launch_bounds__(256, 2) void gemm2_down(
    const u16* __restrict__ Hd, const float* __restrict__ Wd,
    float* __restrict__ Out, long sH, long sW, long sO) {
  const int z = blockIdx.z;
  Hd += (long)z * sH;
  Wd += (long)z * sW;
  Out += (long)z * sO;

  const int bx = blockIdx.x;  // H-col tile (128)
  const int by = blockIdx.y;  // row tile (128)
  const int tid = threadIdx.x;
  const int w = tid >> 6;
  const int lane = tid & 63;
  const int wr = w >> 1, wc = w & 1;
  const int fr = lane & 15, q = lane >> 4, l7 = lane & 7;

  __shared__ __attribute__((aligned(16))) u16 lds[2 * 16384];

  const int srow8 = lane >> 3;
  const int sgran = (lane & 7) ^ (lane >> 3);
  const u16* gA = Hd + (size_t)(by * 128 + srow8) * F_ + sgran * 8;
  const float4* gB4 =
      (const float4*)Wd + (size_t)(bx * 128 + srow8) * (F_ / 4) + sgran * 2;

  const size_t r0_ = (size_t)w * 8 * (F_ / 4);
  const size_t r1_ = (size_t)(4 + w) * 8 * (F_ / 4);
  const size_t r2_ = (size_t)(8 + w) * 8 * (F_ / 4);
  const size_t r3_ = (size_t)(12 + w) * 8 * (F_ / 4);
  const int o0_ = 8192 + w * 512 + lane * 8;
  const int o1_ = 8192 + (4 + w) * 512 + lane * 8;
  const int o2_ = 8192 + (8 + w) * 512 + lane * 8;
  const int o3_ = 8192 + (12 + w) * 512 + lane * 8;

  auto stageA = [&](int t, int buf) {
    u16* L = lds + buf * 16384;
    const int ko = t * 64;
#pragma unroll
    for (int i = 0; i < 4; ++i) {
      const int c = i * 4 + w;
      gload16(gA + (size_t)(c * 8) * F_ + ko, L + c * 512 + lane * 8);
    }
  };

  f32x4 acc[4][4] = {};

  auto comp = [&](int buf) {
    const u16* L = lds + buf * 16384;
#pragma unroll
    for (int ks = 0; ks < 2; ++ks) {
      const int seg = (((ks << 2) + q) ^ l7) << 3;
      bf16x8 a[4], b[4];
#pragma unroll
      for (int mi = 0; mi < 4; ++mi)
        a[mi] = *(const bf16x8*)&L[(wr * 64 + mi * 16 + fr) * 64 + seg];
#pragma unroll
      for (int ni = 0; ni < 4; ++ni)
        b[ni] = *(const bf16x8*)&L[8192 + (wc * 64 + ni * 16 + fr) * 64 + seg];
      __builtin_amdgcn_s_setprio(1);
#pragma unroll
      for (int mi = 0; mi < 4; ++mi)
#pragma unroll
        for (int ni = 0; ni < 4; ++ni) mfma_b(acc[mi][ni], a[mi], b[ni]);
      __builtin_amdgcn_s_setprio(0);
    }
  };

  DECL_RB(pa);
  DECL_RB(pb);
  const int NT = F_ / 64;  // 64
  LOADB(pa, 0);
  stageA(0, 0);
  LOADB(pb, 1);
  stageA(1, 1);
  WAITV(16);
  WRITEB(0, pa);
  WAITV(12);
  LGKM0;
  BARF;
  for (int t = 0; t < NT - 2; t += 2) {
    comp(0);
    BARF;
    LOADB(pa, t + 2);
    stageA(t + 2, 0);
    WAITV(16);
    WRITEB(1, pb);
    WAITV(12);
    LGKM0;
    BARF;
    comp(1);
    BARF;
    LOADB(pb, t + 3);
    stageA(t + 3, 1);
    WAITV(16);
    WRITEB(0, pa);
    WAITV(12);
    LGKM0;
    BARF;
  }
  comp(0);
  BARF;
  WAITV(4);
  WRITEB(1, pb);
  WAITV(0);
  LGKM0;
  BARF;
  comp(1);

  const int row0 = by * 128 + wr * 64 + q * 4;
  const int col0 = bx * 128 + wc * 64 + fr;
#pragma unroll
  for (int mi = 0; mi < 4; ++mi)
#pragma unroll
    for (int ni = 0; ni < 4; ++ni)
#pragma unroll
      for (int j = 0; j < 4; ++j)
        Out[(size_t)(row0 + mi * 16 + j) * H_ + col0 + ni * 16] =
            acc[mi][ni][j];
}

// ---------- host ----------

extern "C" void kernel_launch(void* const* d_in, const int* in_sizes, int n_in,
                              void* d_out, int out_size, void* d_ws,
                              size_t ws_size, hipStream_t stream) {
  (void)in_sizes;
  (void)n_in;
  (void)out_size;
  const float* x = (const float*)d_in[0];
  const float* wgu = (const float*)d_in[1];
  const float* wdn = (const float*)d_in[2];
  float* out = (float*)d_out;
  u16* ws = (u16*)d_ws;

  const size_t xbN = (size_t)T_ * H_;
  const size_t hidN = (size_t)T_ * F_;
  const size_t fullBytes = (xbN + hidN) * 2;  // 201 MiB

  dim3 cblk(256), gblk(256);

  if (ws_size >= fullBytes) {
    u16* xb = ws;
    u16* hid = xb + xbN;
    cvt_kernel<<<1024, cblk, 0, stream>>>(x, xb, (long)(xbN / 4));
    gemm1_silu<<<dim3(F_ / 64, TE_ / 128, E_), gblk, 0, stream>>>(
        xb, wgu, hid, (long)TE_ * H_, (long)2 * F_ * H_, (long)TE_ * F_);
    gemm2_down<<<dim3(H_ / 128, TE_ / 128, E_), gblk, 0, stream>>>(
        hid, wdn, out, (long)TE_ * F_, (long)H_ * F_, (long)TE_ * H_);
  } else {
    u16* xb = ws;
    u16* hid = xb + (size_t)TE_ * H_;
    for (int e = 0; e < E_; ++e) {
      cvt_kernel<<<512, cblk, 0, stream>>>(x + (size_t)e * TE_ * H_, xb,
                                           (long)((size_t)TE_ * H_ / 4));
      gemm1_silu<<<dim3(F_ / 64, TE_ / 128, 1), gblk, 0, stream>>>(
          xb, wgu + (size_t)e * 2 * F_ * H_, hid, 0, 0, 0);
      gemm2_down<<<dim3(H_ / 128, TE_ / 128, 1), gblk, 0, stream>>>(
          hid, wdn + (size_t)e * H_ * F_, out + (size_t)e * TE_ * H_, 0, 0, 0);
    }
  }
}

// Round 13
// 1076.222 us; speedup vs baseline: 1.2413x; 1.2413x over previous
//
#include <hip/hip_runtime.h>
#include <stdint.h>

typedef unsigned short u16;
typedef unsigned int u32;
typedef short bf16x8 __attribute__((ext_vector_type(8)));
typedef float f32x4 __attribute__((ext_vector_type(4)));

#define E_ 8
#define H_ 2048
#define F_ 4096
#define T_ 16384
#define TE_ 2048

#define WAITV(n) asm volatile("s_waitcnt vmcnt(" #n ")" ::: "memory")
#define BARF                       \
  do {                             \
    asm volatile("" ::: "memory"); \
    __builtin_amdgcn_s_barrier();  \
    asm volatile("" ::: "memory"); \
  } while (0)

__device__ __forceinline__ u16 f2bf(float f) {
  u32 u = __builtin_bit_cast(u32, f);
  u32 r = (u + 0x7FFFu + ((u >> 16) & 1u)) >> 16;  // RNE
  return (u16)r;
}

__device__ __forceinline__ void gload16(const u16* g, u16* l) {
  __builtin_amdgcn_global_load_lds(
      (__attribute__((address_space(1))) void*)g,
      (__attribute__((address_space(3))) void*)l, 16, 0, 0);
}

__device__ __forceinline__ void mfma_b(f32x4& acc, bf16x8 a, bf16x8 b) {
  asm volatile("v_mfma_f32_16x16x32_bf16 %0, %1, %2, %0"
               : "+v"(acc)
               : "v"(a), "v"(b));
}

// ---------- fp32 -> bf16 convert (3 separate launches, proven) ----------

__global__ __launch_bounds__(256) void cvt_kernel(const float* __restrict__ src,
                                                  u16* __restrict__ dst,
                                                  long n4) {
  long i = (long)blockIdx.x * blockDim.x + threadIdx.x;
  long stride = (long)gridDim.x * blockDim.x;
  const float4* s4 = (const float4*)src;
  uint2* d4 = (uint2*)dst;
  for (; i < n4; i += stride) {
    float4 v = s4[i];
    uint2 o;
    o.x = (u32)f2bf(v.x) | ((u32)f2bf(v.y) << 16);
    o.y = (u32)f2bf(v.z) | ((u32)f2bf(v.w) << 16);
    d4[i] = o;
  }
}

// ============ GEMM1 fused: hidden = silu(x@Wg^T) * (x@Wu^T) ============
// (round-7/8 proven: ~540us, MfmaUtil ~49, 0 conflicts)
// 256-thread / 4-wave blocks, tile 128 rows x 64 hidden cols, BK=64,
// ring-2 LDS = 64 KiB -> 2 blocks/CU (two independent barrier domains).

__global__ __launch_bounds__(256, 2) void gemm1_silu(
    const u16* __restrict__ Xb, const u16* __restrict__ Wgu,
    u16* __restrict__ Hid, long sX, long sW, long sH) {
  const int z = blockIdx.z;
  Xb += (long)z * sX;
  Wgu += (long)z * sW;
  Hid += (long)z * sH;

  const int bx = blockIdx.x;  // hidden-col tile (64)
  const int by = blockIdx.y;  // row tile (128)
  const int tid = threadIdx.x;
  const int w = tid >> 6;  // 0..3
  const int lane = tid & 63;
  const int wr = w >> 1, wc = w & 1;
  const int fr = lane & 15, q = lane >> 4, l7 = lane & 7;

  // per-buf (16384 el = 32 KB): A[128][64] @0, Bg[64][64] @8192, Bu @12288
  __shared__ __attribute__((aligned(16))) u16 lds[2 * 16384];

  const int srow8 = lane >> 3;
  const int sgran = (lane & 7) ^ (lane >> 3);
  const u16* gA = Xb + (size_t)(by * 128 + srow8) * H_ + sgran * 8;
  const u16* gBg = Wgu + (size_t)(bx * 64 + srow8) * H_ + sgran * 8;
  const u16* gBu = gBg + (size_t)F_ * H_;

  auto stage = [&](int t, int buf) {
    u16* L = lds + buf * 16384;
    const int ko = t * 64;
#pragma unroll
    for (int i = 0; i < 4; ++i) {
      const int c = i * 4 + w;
      gload16(gA + (size_t)(c * 8) * H_ + ko, L + c * 512 + lane * 8);
    }
#pragma unroll
    for (int i = 0; i < 2; ++i) {
      const int c = i * 4 + w;
      gload16(gBg + (size_t)(c * 8) * H_ + ko, L + 8192 + c * 512 + lane * 8);
      gload16(gBu + (size_t)(c * 8) * H_ + ko, L + 12288 + c * 512 + lane * 8);
    }
  };

  f32x4 accG[4][2] = {};
  f32x4 accU[4][2] = {};

  auto comp = [&](int buf) {
    const u16* L = lds + buf * 16384;
#pragma unroll
    for (int ks = 0; ks < 2; ++ks) {
      const int seg = (((ks << 2) + q) ^ l7) << 3;
      bf16x8 a[4], bg[2], bu[2];
#pragma unroll
      for (int mi = 0; mi < 4; ++mi)
        a[mi] = *(const bf16x8*)&L[(wr * 64 + mi * 16 + fr) * 64 + seg];
#pragma unroll
      for (int ni = 0; ni < 2; ++ni) {
        bg[ni] = *(const bf16x8*)&L[8192 + (wc * 32 + ni * 16 + fr) * 64 + seg];
        bu[ni] =
            *(const bf16x8*)&L[12288 + (wc * 32 + ni * 16 + fr) * 64 + seg];
      }
      __builtin_amdgcn_s_setprio(1);
#pragma unroll
      for (int mi = 0; mi < 4; ++mi)
#pragma unroll
        for (int ni = 0; ni < 2; ++ni) {
          mfma_b(accG[mi][ni], a[mi], bg[ni]);
          mfma_b(accU[mi][ni], a[mi], bu[ni]);
        }
      __builtin_amdgcn_s_setprio(0);
    }
  };

  const int NT = H_ / 64;  // 32
  stage(0, 0);
  stage(1, 1);
  for (int t = 0; t < NT - 1; ++t) {
    WAITV(8);
    BARF;
    comp(t & 1);
    BARF;
    if (t + 2 < NT) stage(t + 2, t & 1);
  }
  WAITV(0);
  BARF;
  comp((NT - 1) & 1);

  const int row0 = by * 128 + wr * 64 + q * 4;
  const int col0 = bx * 64 + wc * 32 + fr;
#pragma unroll
  for (int mi = 0; mi < 4; ++mi)
#pragma unroll
    for (int ni = 0; ni < 2; ++ni)
#pragma unroll
      for (int j = 0; j < 4; ++j) {
        float g = accG[mi][ni][j];
        float u = accU[mi][ni][j];
        float h = (g / (1.f + __expf(-g))) * u;
        Hid[(size_t)(row0 + mi * 16 + j) * F_ + col0 + ni * 16] = f2bf(h);
      }
}

// ============ GEMM2: out = hidden @ w_down^T (fp32 out) ============
// Same m114 structure: 256-thread / 4-wave blocks, tile 128 rows x 128
// cols, wave tile 64x64, BK=64, ring-2 LDS = 64 KiB -> 2 blocks/CU.

__global__ __launch_bounds__(256, 2) void gemm2_down(
    const u16* __restrict__ Hd, const u16* __restrict__ Wd,
    float* __restrict__ Out, long sH, long sW, long sO) {
  const int z = blockIdx.z;
  Hd += (long)z * sH;
  Wd += (long)z * sW;
  Out += (long)z * sO;

  const int bx = blockIdx.x;  // H-col tile (128)
  const int by = blockIdx.y;  // row tile (128)
  const int tid = threadIdx.x;
  const int w = tid >> 6;  // 0..3
  const int lane = tid & 63;
  const int wr = w >> 1, wc = w & 1;
  const int fr = lane & 15, q = lane >> 4, l7 = lane & 7;

  // per-buf (16384 el = 32 KB): A[128][64] @0, B[128][64] @8192
  __shared__ __attribute__((aligned(16))) u16 lds[2 * 16384];

  const int srow8 = lane >> 3;
  const int sgran = (lane & 7) ^ (lane >> 3);
  const u16* gA = Hd + (size_t)(by * 128 + srow8) * F_ + sgran * 8;
  const u16* gB = Wd + (size_t)(bx * 128 + srow8) * F_ + sgran * 8;

  auto stage = [&](int t, int buf) {
    u16* L = lds + buf * 16384;
    const int ko = t * 64;
#pragma unroll
    for (int i = 0; i < 4; ++i) {
      const int c = i * 4 + w;
      gload16(gA + (size_t)(c * 8) * F_ + ko, L + c * 512 + lane * 8);
      gload16(gB + (size_t)(c * 8) * F_ + ko, L + 8192 + c * 512 + lane * 8);
    }
  };

  f32x4 acc[4][4] = {};

  auto comp = [&](int buf) {
    const u16* L = lds + buf * 16384;
#pragma unroll
    for (int ks = 0; ks < 2; ++ks) {
      const int seg = (((ks << 2) + q) ^ l7) << 3;
      bf16x8 a[4], b[4];
#pragma unroll
      for (int mi = 0; mi < 4; ++mi)
        a[mi] = *(const bf16x8*)&L[(wr * 64 + mi * 16 + fr) * 64 + seg];
#pragma unroll
      for (int ni = 0; ni < 4; ++ni)
        b[ni] = *(const bf16x8*)&L[8192 + (wc * 64 + ni * 16 + fr) * 64 + seg];
      __builtin_amdgcn_s_setprio(1);
#pragma unroll
      for (int mi = 0; mi < 4; ++mi)
#pragma unroll
        for (int ni = 0; ni < 4; ++ni) mfma_b(acc[mi][ni], a[mi], b[ni]);
      __builtin_amdgcn_s_setprio(0);
    }
  };

  const int NT = F_ / 64;  // 64
  stage(0, 0);
  stage(1, 1);
  for (int t = 0; t < NT - 1; ++t) {
    WAITV(8);
    BARF;
    comp(t & 1);
    BARF;
    if (t + 2 < NT) stage(t + 2, t & 1);
  }
  WAITV(0);
  BARF;
  comp((NT - 1) & 1);

  const int row0 = by * 128 + wr * 64 + q * 4;
  const int col0 = bx * 128 + wc * 64 + fr;
#pragma unroll
  for (int mi = 0; mi < 4; ++mi)
#pragma unroll
    for (int ni = 0; ni < 4; ++ni)
#pragma unroll
      for (int j = 0; j < 4; ++j)
        Out[(size_t)(row0 + mi * 16 + j) * H_ + col0 + ni * 16] =
            acc[mi][ni][j];
}

// ---------- host ----------

extern "C" void kernel_launch(void* const* d_in, const int* in_sizes, int n_in,
                              void* d_out, int out_size, void* d_ws,
                              size_t ws_size, hipStream_t stream) {
  (void)in_sizes;
  (void)n_in;
  (void)out_size;
  const float* x = (const float*)d_in[0];
  const float* wgu = (const float*)d_in[1];
  const float* wdn = (const float*)d_in[2];
  float* out = (float*)d_out;
  u16* ws = (u16*)d_ws;

  const size_t xbN = (size_t)T_ * H_;
  const size_t wguN = (size_t)E_ * 2 * F_ * H_;
  const size_t wdnN = (size_t)E_ * H_ * F_;
  const size_t hidN = (size_t)T_ * F_;
  const size_t fullBytes = (xbN + wguN + wdnN + hidN) * 2;  // 576 MiB

  dim3 cblk(256), gblk(256);

  if (ws_size >= fullBytes) {
    u16* xb = ws;
    u16* wgub = xb + xbN;
    u16* wdnb = wgub + wguN;
    u16* hid = wdnb + wdnN;
    cvt_kernel<<<2048, cblk, 0, stream>>>(x, xb, (long)(xbN / 4));
    cvt_kernel<<<4096, cblk, 0, stream>>>(wgu, wgub, (long)(wguN / 4));
    cvt_kernel<<<4096, cblk, 0, stream>>>(wdn, wdnb, (long)(wdnN / 4));
    gemm1_silu<<<dim3(F_ / 64, TE_ / 128, E_), gblk, 0, stream>>>(
        xb, wgub, hid, (long)TE_ * H_, (long)2 * F_ * H_, (long)TE_ * F_);
    gemm2_down<<<dim3(H_ / 128, TE_ / 128, E_), gblk, 0, stream>>>(
        hid, wdnb, out, (long)TE_ * F_, (long)H_ * F_, (long)TE_ * H_);
  } else {
    u16* xb = ws;
    u16* wgub = xb + (size_t)TE_ * H_;
    u16* wdnb = wgub + (size_t)2 * F_ * H_;
    u16* hid = wdnb + (size_t)H_ * F_;
    for (int e = 0; e < E_; ++e) {
      cvt_kernel<<<1024, cblk, 0, stream>>>(x + (size_t)e * TE_ * H_, xb,
                                            (long)((size_t)TE_ * H_ / 4));
      cvt_kernel<<<2048, cblk, 0, stream>>>(wgu + (size_t)e * 2 * F_ * H_, wgub,
                                            (long)((size_t)2 * F_ * H_ / 4));
      cvt_kernel<<<2048, cblk, 0, stream>>>(wdn + (size_t)e * H_ * F_, wdnb,
                                            (long)((size_t)H_ * F_ / 4));
      gemm1_silu<<<dim3(F_ / 64, TE_ / 128, 1), gblk, 0, stream>>>(xb, wgub,
                                                                   hid, 0, 0,
                                                                   0);
      gemm2_down<<<dim3(H_ / 128, TE_ / 128, 1), gblk, 0, stream>>>(
          hid, wdnb, out + (size_t)e * TE_ * H_, 0, 0, 0);
    }
  }
}

// Round 14
// 1056.035 us; speedup vs baseline: 1.2650x; 1.0191x over previous
//
#include <hip/hip_runtime.h>
#include <stdint.h>

typedef unsigned short u16;
typedef unsigned int u32;
typedef short bf16x8 __attribute__((ext_vector_type(8)));
typedef float f32x4 __attribute__((ext_vector_type(4)));

#define E_ 8
#define H_ 2048
#define F_ 4096
#define T_ 16384
#define TE_ 2048

#define WAITV(n) asm volatile("s_waitcnt vmcnt(" #n ")" ::: "memory")
#define BARF                       \
  do {                             \
    asm volatile("" ::: "memory"); \
    __builtin_amdgcn_s_barrier();  \
    asm volatile("" ::: "memory"); \
  } while (0)

__device__ __forceinline__ u16 f2bf(float f) {
  u32 u = __builtin_bit_cast(u32, f);
  u32 r = (u + 0x7FFFu + ((u >> 16) & 1u)) >> 16;  // RNE
  return (u16)r;
}

__device__ __forceinline__ void gload16(const u16* g, u16* l) {
  __builtin_amdgcn_global_load_lds(
      (__attribute__((address_space(1))) void*)g,
      (__attribute__((address_space(3))) void*)l, 16, 0, 0);
}

__device__ __forceinline__ void mfma_b(f32x4& acc, bf16x8 a, bf16x8 b) {
  asm volatile("v_mfma_f32_16x16x32_bf16 %0, %1, %2, %0"
               : "+v"(acc)
               : "v"(a), "v"(b));
}

// ---------- fp32 -> bf16 convert (x + w_gate_up; w_down fused in gemm1) ----

__global__ __launch_bounds__(256) void cvt_kernel(const float* __restrict__ src,
                                                  u16* __restrict__ dst,
                                                  long n4) {
  long i = (long)blockIdx.x * blockDim.x + threadIdx.x;
  long stride = (long)gridDim.x * blockDim.x;
  const float4* s4 = (const float4*)src;
  uint2* d4 = (uint2*)dst;
  for (; i < n4; i += stride) {
    float4 v = s4[i];
    uint2 o;
    o.x = (u32)f2bf(v.x) | ((u32)f2bf(v.y) << 16);
    o.y = (u32)f2bf(v.z) | ((u32)f2bf(v.w) << 16);
    d4[i] = o;
  }
}

// ============ GEMM1 fused: hidden = silu(x@Wg^T) * (x@Wu^T) ============
// (round-8/13 proven: ~540us, MfmaUtil ~49, 0 conflicts)
// 256-thread / 4-wave blocks, tile 128 rows x 64 hidden cols, BK=64,
// ring-2 LDS = 64 KiB -> 2 blocks/CU (two independent barrier domains).
// TAIL FUSION: after the epilogue each block converts a 2048-float4 slice
// of w_down fp32->bf16 (slice = linear block id; grid unchanged — round-9's
// regression came from grid perturbation, not the extra traffic). gemm1
// runs at ~2.0 TB/s so this rides idle HBM BW; output needed only by gemm2.

__global__ __launch_bounds__(256, 2) void gemm1_silu(
    const u16* __restrict__ Xb, const u16* __restrict__ Wgu,
    u16* __restrict__ Hid, const float* __restrict__ WdnSrc,
    u16* __restrict__ WdnDst, long sX, long sW, long sH) {
  const int z = blockIdx.z;
  Xb += (long)z * sX;
  Wgu += (long)z * sW;
  Hid += (long)z * sH;

  const int bx = blockIdx.x;  // hidden-col tile (64)
  const int by = blockIdx.y;  // row tile (128)
  const int tid = threadIdx.x;
  const int w = tid >> 6;  // 0..3
  const int lane = tid & 63;
  const int wr = w >> 1, wc = w & 1;
  const int fr = lane & 15, q = lane >> 4, l7 = lane & 7;

  // per-buf (16384 el = 32 KB): A[128][64] @0, Bg[64][64] @8192, Bu @12288
  __shared__ __attribute__((aligned(16))) u16 lds[2 * 16384];

  const int srow8 = lane >> 3;
  const int sgran = (lane & 7) ^ (lane >> 3);
  const u16* gA = Xb + (size_t)(by * 128 + srow8) * H_ + sgran * 8;
  const u16* gBg = Wgu + (size_t)(bx * 64 + srow8) * H_ + sgran * 8;
  const u16* gBu = gBg + (size_t)F_ * H_;

  auto stage = [&](int t, int buf) {
    u16* L = lds + buf * 16384;
    const int ko = t * 64;
#pragma unroll
    for (int i = 0; i < 4; ++i) {
      const int c = i * 4 + w;
      gload16(gA + (size_t)(c * 8) * H_ + ko, L + c * 512 + lane * 8);
    }
#pragma unroll
    for (int i = 0; i < 2; ++i) {
      const int c = i * 4 + w;
      gload16(gBg + (size_t)(c * 8) * H_ + ko, L + 8192 + c * 512 + lane * 8);
      gload16(gBu + (size_t)(c * 8) * H_ + ko, L + 12288 + c * 512 + lane * 8);
    }
  };

  f32x4 accG[4][2] = {};
  f32x4 accU[4][2] = {};

  auto comp = [&](int buf) {
    const u16* L = lds + buf * 16384;
#pragma unroll
    for (int ks = 0; ks < 2; ++ks) {
      const int seg = (((ks << 2) + q) ^ l7) << 3;
      bf16x8 a[4], bg[2], bu[2];
#pragma unroll
      for (int mi = 0; mi < 4; ++mi)
        a[mi] = *(const bf16x8*)&L[(wr * 64 + mi * 16 + fr) * 64 + seg];
#pragma unroll
      for (int ni = 0; ni < 2; ++ni) {
        bg[ni] = *(const bf16x8*)&L[8192 + (wc * 32 + ni * 16 + fr) * 64 + seg];
        bu[ni] =
            *(const bf16x8*)&L[12288 + (wc * 32 + ni * 16 + fr) * 64 + seg];
      }
      __builtin_amdgcn_s_setprio(1);
#pragma unroll
      for (int mi = 0; mi < 4; ++mi)
#pragma unroll
        for (int ni = 0; ni < 2; ++ni) {
          mfma_b(accG[mi][ni], a[mi], bg[ni]);
          mfma_b(accU[mi][ni], a[mi], bu[ni]);
        }
      __builtin_amdgcn_s_setprio(0);
    }
  };

  const int NT = H_ / 64;  // 32
  stage(0, 0);
  stage(1, 1);
  for (int t = 0; t < NT - 1; ++t) {
    WAITV(8);
    BARF;
    comp(t & 1);
    BARF;
    if (t + 2 < NT) stage(t + 2, t & 1);
  }
  WAITV(0);
  BARF;
  comp((NT - 1) & 1);

  const int row0 = by * 128 + wr * 64 + q * 4;
  const int col0 = bx * 64 + wc * 32 + fr;
#pragma unroll
  for (int mi = 0; mi < 4; ++mi)
#pragma unroll
    for (int ni = 0; ni < 2; ++ni)
#pragma unroll
      for (int j = 0; j < 4; ++j) {
        float g = accG[mi][ni][j];
        float u = accU[mi][ni][j];
        float h = (g / (1.f + __expf(-g))) * u;
        Hid[(size_t)(row0 + mi * 16 + j) * F_ + col0 + ni * 16] = f2bf(h);
      }

  // tail: convert this block's w_down slice (2048 float4) fp32 -> bf16
  {
    const long cid = (long)bx + 64L * ((long)by + 16L * z);
    const float4* s4 = (const float4*)WdnSrc;
    uint2* d4 = (uint2*)WdnDst;
    const long base = cid * 2048 + tid;
#pragma unroll
    for (int i = 0; i < 8; ++i) {
      float4 v = s4[base + i * 256];
      uint2 o;
      o.x = (u32)f2bf(v.x) | ((u32)f2bf(v.y) << 16);
      o.y = (u32)f2bf(v.z) | ((u32)f2bf(v.w) << 16);
      d4[base + i * 256] = o;
    }
  }
}

// ============ GEMM2: out = hidden @ w_down^T (fp32 out) ============
// Same m114 structure: 256-thread / 4-wave blocks, tile 128 rows x 128
// cols, wave tile 64x64, BK=64, ring-2 LDS = 64 KiB -> 2 blocks/CU.

__global__ __launch_bounds__(256, 2) void gemm2_down(
    const u16* __restrict__ Hd, const u16* __restrict__ Wd,
    float* __restrict__ Out, long sH, long sW, long sO) {
  const int z = blockIdx.z;
  Hd += (long)z * sH;
  Wd += (long)z * sW;
  Out += (long)z * sO;

  const int bx = blockIdx.x;  // H-col tile (128)
  const int by = blockIdx.y;  // row tile (128)
  const int tid = threadIdx.x;
  const int w = tid >> 6;  // 0..3
  const int lane = tid & 63;
  const int wr = w >> 1, wc = w & 1;
  const int fr = lane & 15, q = lane >> 4, l7 = lane & 7;

  // per-buf (16384 el = 32 KB): A[128][64] @0, B[128][64] @8192
  __shared__ __attribute__((aligned(16))) u16 lds[2 * 16384];

  const int srow8 = lane >> 3;
  const int sgran = (lane & 7) ^ (lane >> 3);
  const u16* gA = Hd + (size_t)(by * 128 + srow8) * F_ + sgran * 8;
  const u16* gB = Wd + (size_t)(bx * 128 + srow8) * F_ + sgran * 8;

  auto stage = [&](int t, int buf) {
    u16* L = lds + buf * 16384;
    const int ko = t * 64;
#pragma unroll
    for (int i = 0; i < 4; ++i) {
      const int c = i * 4 + w;
      gload16(gA + (size_t)(c * 8) * F_ + ko, L + c * 512 + lane * 8);
      gload16(gB + (size_t)(c * 8) * F_ + ko, L + 8192 + c * 512 + lane * 8);
    }
  };

  f32x4 acc[4][4] = {};

  auto comp = [&](int buf) {
    const u16* L = lds + buf * 16384;
#pragma unroll
    for (int ks = 0; ks < 2; ++ks) {
      const int seg = (((ks << 2) + q) ^ l7) << 3;
      bf16x8 a[4], b[4];
#pragma unroll
      for (int mi = 0; mi < 4; ++mi)
        a[mi] = *(const bf16x8*)&L[(wr * 64 + mi * 16 + fr) * 64 + seg];
#pragma unroll
      for (int ni = 0; ni < 4; ++ni)
        b[ni] = *(const bf16x8*)&L[8192 + (wc * 64 + ni * 16 + fr) * 64 + seg];
      __builtin_amdgcn_s_setprio(1);
#pragma unroll
      for (int mi = 0; mi < 4; ++mi)
#pragma unroll
        for (int ni = 0; ni < 4; ++ni) mfma_b(acc[mi][ni], a[mi], b[ni]);
      __builtin_amdgcn_s_setprio(0);
    }
  };

  const int NT = F_ / 64;  // 64
  stage(0, 0);
  stage(1, 1);
  for (int t = 0; t < NT - 1; ++t) {
    WAITV(8);
    BARF;
    comp(t & 1);
    BARF;
    if (t + 2 < NT) stage(t + 2, t & 1);
  }
  WAITV(0);
  BARF;
  comp((NT - 1) & 1);

  const int row0 = by * 128 + wr * 64 + q * 4;
  const int col0 = bx * 128 + wc * 64 + fr;
#pragma unroll
  for (int mi = 0; mi < 4; ++mi)
#pragma unroll
    for (int ni = 0; ni < 4; ++ni)
#pragma unroll
      for (int j = 0; j < 4; ++j)
        Out[(size_t)(row0 + mi * 16 + j) * H_ + col0 + ni * 16] =
            acc[mi][ni][j];
}

// ---------- host ----------

extern "C" void kernel_launch(void* const* d_in, const int* in_sizes, int n_in,
                              void* d_out, int out_size, void* d_ws,
                              size_t ws_size, hipStream_t stream) {
  (void)in_sizes;
  (void)n_in;
  (void)out_size;
  const float* x = (const float*)d_in[0];
  const float* wgu = (const float*)d_in[1];
  const float* wdn = (const float*)d_in[2];
  float* out = (float*)d_out;
  u16* ws = (u16*)d_ws;

  const size_t xbN = (size_t)T_ * H_;
  const size_t wguN = (size_t)E_ * 2 * F_ * H_;
  const size_t wdnN = (size_t)E_ * H_ * F_;
  const size_t hidN = (size_t)T_ * F_;
  const size_t fullBytes = (xbN + wguN + wdnN + hidN) * 2;  // 576 MiB

  dim3 cblk(256), gblk(256);

  if (ws_size >= fullBytes) {
    u16* xb = ws;
    u16* wgub = xb + xbN;
    u16* wdnb = wgub + wguN;
    u16* hid = wdnb + wdnN;
    cvt_kernel<<<2048, cblk, 0, stream>>>(x, xb, (long)(xbN / 4));
    cvt_kernel<<<4096, cblk, 0, stream>>>(wgu, wgub, (long)(wguN / 4));
    // w_down cvt fused into gemm1 tail: 8192 blocks x 2048 f4 = wdnN/4
    gemm1_silu<<<dim3(F_ / 64, TE_ / 128, E_), gblk, 0, stream>>>(
        xb, wgub, hid, wdn, wdnb, (long)TE_ * H_, (long)2 * F_ * H_,
        (long)TE_ * F_);
    gemm2_down<<<dim3(H_ / 128, TE_ / 128, E_), gblk, 0, stream>>>(
        hid, wdnb, out, (long)TE_ * F_, (long)H_ * F_, (long)TE_ * H_);
  } else {
    u16* xb = ws;
    u16* wgub = xb + (size_t)TE_ * H_;
    u16* wdnb = wgub + (size_t)2 * F_ * H_;
    u16* hid = wdnb + (size_t)H_ * F_;
    for (int e = 0; e < E_; ++e) {
      cvt_kernel<<<1024, cblk, 0, stream>>>(x + (size_t)e * TE_ * H_, xb,
                                            (long)((size_t)TE_ * H_ / 4));
      cvt_kernel<<<2048, cblk, 0, stream>>>(wgu + (size_t)e * 2 * F_ * H_, wgub,
                                            (long)((size_t)2 * F_ * H_ / 4));
      // per-expert: 1024 blocks x 2048 f4 = H_*F_/4 exactly
      gemm1_silu<<<dim3(F_ / 64, TE_ / 128, 1), gblk, 0, stream>>>(
          xb, wgub, hid, wdn + (size_t)e * H_ * F_, wdnb, 0, 0, 0);
      gemm2_down<<<dim3(H_ / 128, TE_ / 128, 1), gblk, 0, stream>>>(
          hid, wdnb, out + (size_t)e * TE_ * H_, 0, 0, 0);
    }
  }
}